// Round 14
// baseline (118.052 us; speedup 1.0000x reference)
//
#include <hip/hip_runtime.h>
#include <cstdint>
#include <cstddef>

#define SEQ   3072
#define DIM   1280
#define NH    16
#define HD    80
#define HDP   96
#define NSEG  4
#define SEGL  768
#define QKVN  3840

typedef __attribute__((ext_vector_type(8))) short short8;
typedef __attribute__((ext_vector_type(4))) short short4v;
typedef __attribute__((ext_vector_type(4))) float f32x4;
typedef __bf16 bf16x8 __attribute__((ext_vector_type(8)));

__device__ __forceinline__ f32x4 mfma16(short8 a, short8 b, f32x4 c) {
  return __builtin_amdgcn_mfma_f32_16x16x32_bf16(
      __builtin_bit_cast(bf16x8, a), __builtin_bit_cast(bf16x8, b), c, 0, 0, 0);
}

__device__ __forceinline__ float bf2f(short u) {
  union { unsigned int i; float f; } v;
  v.i = ((unsigned int)(unsigned short)u) << 16;
  return v.f;
}
__device__ __forceinline__ short f2bf(float f) {
  union { float f; unsigned int i; } v; v.f = f;
  unsigned int x = v.i;
  unsigned int r = (x + 0x7fffu + ((x >> 16) & 1u)) >> 16;
  return (short)r;
}

// ---------------- fp32 -> bf16 convert (hidden + w_qkv) ---------------------
__global__ void cvt2(const float* __restrict__ a, short* __restrict__ oa, int na,
                     const float* __restrict__ b, short* __restrict__ ob, int nb) {
  int i = blockIdx.x * 256 + threadIdx.x;
  const float* src; short* dst; int off;
  if (i < na) { src = a; dst = oa; off = i; }
  else if (i < na + nb) { src = b; dst = ob; off = i - na; }
  else return;
  float4 v = ((const float4*)src)[off];
  short4v o;
  o[0] = f2bf(v.x); o[1] = f2bf(v.y); o[2] = f2bf(v.z); o[3] = f2bf(v.w);
  ((short4v*)dst)[off] = o;
}

// ===== QKV GEMM: 256x192, BK=64, 4-phase/K-tile (T3 barrier-pair template) ==
// Phase k: {ds_read A m-pair (+B in ph0), issue stage group, [counted vmcnt],
// barrier, setprio(1), 12 MFMA, setprio(0), barrier}. Stages: ph0->B(t+1),
// ph1->AE(t+1), ph2->AL(t+1). Waits: ph1 vmcnt(5) drains AL(t) (read ph2/3);
// ph3 vmcnt(2) drains B+AE(t+1) (read next ph0). Never 0 mid-loop.
#define NKT 20   // K=1280/64

__global__ __launch_bounds__(512, 2)
void gemm_qkv_8ph(const short* __restrict__ A, const short* __restrict__ B,
                  const float* __restrict__ bias, short* __restrict__ C,
                  int N, int K, int nbm, int cpx) {
  __shared__ short As[2][256 * 64];
  __shared__ short Bs[2][192 * 64];
  const int T = threadIdx.x;
  const int w = T >> 6, l = T & 63, g = l >> 4, q = l & 15;
  const int wr = w >> 2, wc = w & 3;
  const int bid = blockIdx.x;
  const int swz = (bid & 7) * cpx + (bid >> 3);   // bijective: grid % 8 == 0
  const int bm = (swz % nbm) * 256;
  const int bn = (swz / nbm) * 192;

  const int sr = T >> 3, ps = T & 7;
  const int gsrc = ps ^ (sr & 7);
  const short* srcA = A + (size_t)(bm + sr) * K + gsrc * 8;
  const short* srcB = B + (size_t)(bn + sr) * K + gsrc * 8;

#define STAGE_B(tt, pb)                                                        \
  do {                                                                         \
    _Pragma("unroll") for (int j = 0; j < 3; ++j)                              \
      __builtin_amdgcn_global_load_lds(                                        \
        (const __attribute__((address_space(1))) void*)(srcB + (size_t)j * 64 * K + (size_t)(tt) * 64), \
        (__attribute__((address_space(3))) void*)(&Bs[pb][j * 4096 + T * 8]),  \
        16, 0, 0);                                                             \
  } while (0)
#define STAGE_AE(tt, pb)                                                       \
  do {                                                                         \
    __builtin_amdgcn_global_load_lds(                                          \
        (const __attribute__((address_space(1))) void*)(srcA + (size_t)(tt) * 64), \
        (__attribute__((address_space(3))) void*)(&As[pb][T * 8]), 16, 0, 0);  \
    __builtin_amdgcn_global_load_lds(                                          \
        (const __attribute__((address_space(1))) void*)(srcA + (size_t)2 * 64 * K + (size_t)(tt) * 64), \
        (__attribute__((address_space(3))) void*)(&As[pb][2 * 4096 + T * 8]),  \
        16, 0, 0);                                                             \
  } while (0)
#define STAGE_AL(tt, pb)                                                       \
  do {                                                                         \
    __builtin_amdgcn_global_load_lds(                                          \
        (const __attribute__((address_space(1))) void*)(srcA + (size_t)1 * 64 * K + (size_t)(tt) * 64), \
        (__attribute__((address_space(3))) void*)(&As[pb][1 * 4096 + T * 8]),  \
        16, 0, 0);                                                             \
    __builtin_amdgcn_global_load_lds(                                          \
        (const __attribute__((address_space(1))) void*)(srcA + (size_t)3 * 64 * K + (size_t)(tt) * 64), \
        (__attribute__((address_space(3))) void*)(&As[pb][3 * 4096 + T * 8]),  \
        16, 0, 0);                                                             \
  } while (0)

  const int s0e = (g ^ (q & 7)) * 8;
  const int rowAe = (wr * 128 + q) * 64;
  const int rowBe = (wc * 48 + q) * 64;

  f32x4 acc[8][3] = {};

  STAGE_B(0, 0); STAGE_AE(0, 0); STAGE_AL(0, 0);
  asm volatile("s_waitcnt vmcnt(0)" ::: "memory");
  __builtin_amdgcn_s_barrier();

#define READ_A(mq)                                                             \
  do {                                                                         \
    _Pragma("unroll") for (int m2 = 0; m2 < 2; ++m2)                           \
      _Pragma("unroll") for (int kk = 0; kk < 2; ++kk)                         \
        af[m2][kk] = *(const short8*)(&As[p][rowAe + ((mq) * 2 + m2) * 1024 + (s0e ^ (kk * 32))]); \
  } while (0)
#define DO_MFMA(mq)                                                            \
  do {                                                                         \
    __builtin_amdgcn_s_setprio(1);                                             \
    _Pragma("unroll") for (int m2 = 0; m2 < 2; ++m2)                           \
      _Pragma("unroll") for (int n = 0; n < 3; ++n)                            \
        _Pragma("unroll") for (int kk = 0; kk < 2; ++kk)                       \
          acc[(mq) * 2 + m2][n] = mfma16(af[m2][kk], bfr[n][kk], acc[(mq) * 2 + m2][n]); \
    __builtin_amdgcn_s_setprio(0);                                             \
  } while (0)

  for (int t = 0; t < NKT; ++t) {
    const int p = t & 1;
    const bool more = (t + 1 < NKT);

    short8 bfr[3][2], af[2][2];

    // ---- phase 0: B frags + A m0,m1; stage B(t+1)
#pragma unroll
    for (int n = 0; n < 3; ++n)
#pragma unroll
      for (int kk = 0; kk < 2; ++kk)
        bfr[n][kk] = *(const short8*)(&Bs[p][rowBe + n * 1024 + (s0e ^ (kk * 32))]);
    READ_A(0);
    if (more) STAGE_B(t + 1, p ^ 1);
    __builtin_amdgcn_s_barrier();
    DO_MFMA(0);
    __builtin_amdgcn_s_barrier();

    // ---- phase 1: A m2,m3; stage AE(t+1); drain AL(t) (read in ph2/ph3)
    READ_A(1);
    if (more) {
      STAGE_AE(t + 1, p ^ 1);
      asm volatile("s_waitcnt vmcnt(5)" ::: "memory");
    } else {
      asm volatile("s_waitcnt vmcnt(0)" ::: "memory");
    }
    __builtin_amdgcn_s_barrier();
    DO_MFMA(1);
    __builtin_amdgcn_s_barrier();

    // ---- phase 2: A m4,m5; stage AL(t+1)
    READ_A(2);
    if (more) STAGE_AL(t + 1, p ^ 1);
    __builtin_amdgcn_s_barrier();
    DO_MFMA(2);
    __builtin_amdgcn_s_barrier();

    // ---- phase 3: A m6,m7; drain B+AE(t+1) (read next ph0)
    READ_A(3);
    if (more) asm volatile("s_waitcnt vmcnt(2)" ::: "memory");
    else      asm volatile("s_waitcnt vmcnt(0)" ::: "memory");
    __builtin_amdgcn_s_barrier();
    DO_MFMA(3);
    __builtin_amdgcn_s_barrier();
  }
#undef READ_A
#undef DO_MFMA

  float bv[3];
#pragma unroll
  for (int n = 0; n < 3; ++n) bv[n] = bias[bn + wc * 48 + n * 16 + q];
#pragma unroll
  for (int m = 0; m < 8; ++m)
#pragma unroll
    for (int n = 0; n < 3; ++n)
#pragma unroll
      for (int r = 0; r < 4; ++r) {
        int row = bm + wr * 128 + m * 16 + g * 4 + r;
        int col = bn + wc * 48 + n * 16 + q;
        C[(size_t)row * N + col] = f2bf(acc[m][n][r] + bv[n]);
      }
#undef STAGE_B
#undef STAGE_AE
#undef STAGE_AL
}

// ------- 128^2 proj GEMM: TRIPLE-buffered, counted-vmcnt, raw barriers ------
template<int OUT_BF16>
__global__ __launch_bounds__(256, 2)
void gemm_bt(const short* __restrict__ A, const short* __restrict__ B,
             const float* __restrict__ bias, void* __restrict__ Cout,
             int M, int N, int K, int nbx, int cpx) {
  __shared__ short As[3][128 * 32];
  __shared__ short Bs[3][128 * 32];
  const int t = threadIdx.x;
  const int w = t >> 6, l = t & 63;
  const int g = l >> 4, q = l & 15;
  const int wr = w >> 1, wc = w & 1;

  const int bid = blockIdx.x;
  const int swz = (bid & 7) * cpx + (bid >> 3);
  const int bm = (swz / nbx) * 128, bn = (swz % nbx) * 128;

  const int srow = l >> 2;
  const int sg = (l & 3) ^ ((l >> 3) & 3);
  const int gsw = g ^ ((q >> 1) & 3);

  const int c0 = w * 2, c1 = w * 2 + 1;
  const short* gA0 = A + (size_t)(bm + c0 * 16 + srow) * K + sg * 8;
  const short* gA1 = A + (size_t)(bm + c1 * 16 + srow) * K + sg * 8;
  const short* gB0 = B + (size_t)(bn + c0 * 16 + srow) * K + sg * 8;
  const short* gB1 = B + (size_t)(bn + c1 * 16 + srow) * K + sg * 8;

#define PSTAGE(kt, pb)                                                         \
  do {                                                                         \
    __builtin_amdgcn_global_load_lds(                                          \
        (const __attribute__((address_space(1))) void*)(gA0 + (size_t)(kt) * 32), \
        (__attribute__((address_space(3))) void*)(&As[pb][c0 * 512 + (l & 3) * 8 + srow * 32]), 16, 0, 0); \
    __builtin_amdgcn_global_load_lds(                                          \
        (const __attribute__((address_space(1))) void*)(gA1 + (size_t)(kt) * 32), \
        (__attribute__((address_space(3))) void*)(&As[pb][c1 * 512 + (l & 3) * 8 + srow * 32]), 16, 0, 0); \
    __builtin_amdgcn_global_load_lds(                                          \
        (const __attribute__((address_space(1))) void*)(gB0 + (size_t)(kt) * 32), \
        (__attribute__((address_space(3))) void*)(&Bs[pb][c0 * 512 + (l & 3) * 8 + srow * 32]), 16, 0, 0); \
    __builtin_amdgcn_global_load_lds(                                          \
        (const __attribute__((address_space(1))) void*)(gB1 + (size_t)(kt) * 32), \
        (__attribute__((address_space(3))) void*)(&Bs[pb][c1 * 512 + (l & 3) * 8 + srow * 32]), 16, 0, 0); \
  } while (0)

  f32x4 acc[4][4] = {};
  const int nkt = K / 32;

  PSTAGE(0, 0);
  PSTAGE(1, 1);

  for (int kt = 0; kt < nkt; ++kt) {
    const int p = kt % 3;
    if (kt + 1 < nkt) asm volatile("s_waitcnt vmcnt(4)" ::: "memory");
    else              asm volatile("s_waitcnt vmcnt(0)" ::: "memory");
    __builtin_amdgcn_s_barrier();
    if (kt + 2 < nkt) PSTAGE(kt + 2, (kt + 2) % 3);

    short8 af[4], bfr[4];
#pragma unroll
    for (int m = 0; m < 4; ++m)
      af[m] = *(const short8*)(&As[p][(wr * 64 + m * 16 + q) * 32 + gsw * 8]);
#pragma unroll
    for (int n = 0; n < 4; ++n)
      bfr[n] = *(const short8*)(&Bs[p][(wc * 64 + n * 16 + q) * 32 + gsw * 8]);
    __builtin_amdgcn_s_setprio(1);
#pragma unroll
    for (int m = 0; m < 4; ++m)
#pragma unroll
      for (int n = 0; n < 4; ++n)
        acc[m][n] = mfma16(af[m], bfr[n], acc[m][n]);
    __builtin_amdgcn_s_setprio(0);
  }
#undef PSTAGE

  float bv[4];
#pragma unroll
  for (int n = 0; n < 4; ++n) bv[n] = bias[bn + wc * 64 + n * 16 + q];

#pragma unroll
  for (int m = 0; m < 4; ++m)
#pragma unroll
    for (int n = 0; n < 4; ++n)
#pragma unroll
      for (int r = 0; r < 4; ++r) {
        int row = bm + wr * 64 + m * 16 + g * 4 + r;
        int col = bn + wc * 64 + n * 16 + q;
        float v = acc[m][n][r] + bv[n];
        if (OUT_BF16)
          ((short*)Cout)[(size_t)row * N + col] = f2bf(v);
        else
          ((float*)Cout)[(size_t)row * N + col] = v;
      }
}

// ---------- fused prep: RoPE(Q,K) + V-transpose + cvt(w_proj) ---------------
#define NB_ROPE 2304
#define NB_VT   768
#define NB_CVT  1600

__global__ __launch_bounds__(256)
void prep_fused(const short* __restrict__ qkv,
                const float* __restrict__ cosp, const float* __restrict__ sinp,
                short* __restrict__ Qp, short* __restrict__ Kp,
                short* __restrict__ Vt,
                const float* __restrict__ wproj, short* __restrict__ wproj_b) {
  __shared__ short T[80][68];
  const int b = blockIdx.x, t = threadIdx.x;

  if (b < NB_ROPE) {
    int tid = b * 256 + t;
    if (tid >= SEQ * NH * 12) return;
    int j = tid % 12;
    int sh = tid / 12;
    int h = sh % NH, s = sh / NH;
    size_t qbase = ((size_t)h * SEQ + s) * HDP;
    if (j >= 10) {
      short8 z = {};
      *(short8*)(Qp + qbase + 80 + (j - 10) * 8) = z;
      *(short8*)(Kp + qbase + 80 + (j - 10) * 8) = z;
      return;
    }
    const int d0 = j * 4;
    const int gb = s * QKVN + h * HD;
    short4v qlo = *(const short4v*)(qkv + gb + d0);
    short4v qhi = *(const short4v*)(qkv + gb + d0 + 40);
    short4v klo = *(const short4v*)(qkv + gb + DIM + d0);
    short4v khi = *(const short4v*)(qkv + gb + DIM + d0 + 40);
    float4 cl = *(const float4*)(cosp + s * HD + d0);
    float4 ch = *(const float4*)(cosp + s * HD + d0 + 40);
    float4 sl = *(const float4*)(sinp + s * HD + d0);
    float4 sh4 = *(const float4*)(sinp + s * HD + d0 + 40);
    const float scale = 0.11180339887498948f;  // 80^-0.5 folded into Q
    short4v qolo, qohi, kolo, kohi;
#pragma unroll
    for (int e = 0; e < 4; ++e) {
      float cle = ((const float*)&cl)[e], che = ((const float*)&ch)[e];
      float sle = ((const float*)&sl)[e], she = ((const float*)&sh4)[e];
      float ql = bf2f(qlo[e]), qh = bf2f(qhi[e]);
      float kl = bf2f(klo[e]), kh = bf2f(khi[e]);
      qolo[e] = f2bf((ql * cle - qh * sle) * scale);
      qohi[e] = f2bf((qh * che + ql * she) * scale);
      kolo[e] = f2bf(kl * cle - kh * sle);
      kohi[e] = f2bf(kh * che + kl * she);
    }
    *(short4v*)(Qp + qbase + d0) = qolo;
    *(short4v*)(Qp + qbase + d0 + 40) = qohi;
    *(short4v*)(Kp + qbase + d0) = kolo;
    *(short4v*)(Kp + qbase + d0 + 40) = kohi;
  } else if (b < NB_ROPE + NB_VT) {
    int vb = b - NB_ROPE;
    const int sblk = vb % 48, h = vb / 48;
    const int s0 = sblk * 64;
#pragma unroll
    for (int j = 0; j < 5; ++j) {
      int i = j * 256 + t;
      int row = i / 20, c4 = i % 20;
      short4v v = *(const short4v*)(qkv + (size_t)(s0 + row) * QKVN + 2 * DIM + h * HD + c4 * 4);
#pragma unroll
      for (int e = 0; e < 4; ++e) T[c4 * 4 + e][row] = v[e];
    }
    __syncthreads();
#pragma unroll
    for (int j = 0; j < 5; ++j) {
      int i = j * 256 + t;
      int d = i / 16, c4 = i % 16;
      short4v v = *(const short4v*)(&T[d][c4 * 4]);
      *(short4v*)(Vt + ((size_t)h * HD + d) * SEQ + s0 + c4 * 4) = v;
    }
  } else {
    int i = (b - NB_ROPE - NB_VT) * 256 + t;
    if (i >= DIM * DIM / 4) return;
    float4 v = ((const float4*)wproj)[i];
    short4v o;
    o[0] = f2bf(v.x); o[1] = f2bf(v.y); o[2] = f2bf(v.z); o[3] = f2bf(v.w);
    ((short4v*)wproj_b)[i] = o;
  }
}

// ---------------- flash attention (R12-exact: 16x16, double-buffered) -------
#define KTILE_B  6144
#define VTILE_B  5120
#define BUF_B    11264

__global__ __launch_bounds__(256, 4)
void attn_kernel(const short* __restrict__ Qp, const short* __restrict__ Kp,
                 const short* __restrict__ Vt, short* __restrict__ att) {
  __shared__ __align__(16) char smem[2 * BUF_B];
  __shared__ short Pbuf[2][4][16][36];

  const int orig = blockIdx.x;
  const int lg = (orig & 7) * 96 + (orig >> 3);
  const int qt = lg % 12;
  const int hs = lg / 12;
  const int seg = hs & 3, h = hs >> 2;

  const int t = threadIdx.x, w = t >> 6, l = t & 63;
  const int g = l >> 4, q = l & 15;
  const int m4 = (q >> 1) & 3;
  const int gm = g ^ m4;
  const int qrow = seg * SEGL + qt * 64 + w * 16;
  const float L2E = 1.4426950408889634f;

  short8 qf[3];
#pragma unroll
  for (int dt = 0; dt < 3; ++dt)
    qf[dt] = *(const short8*)(Qp + ((size_t)h * SEQ + qrow + q) * HDP + dt * 32 + g * 8);

  const char* src0; const char* src1; const char* src2;
  int dst0, dst1, dst2, adv0, adv1, adv2;
  const int nld = (w < 3) ? 3 : 2;
  {
    const char* sArr[3]; int dArr[3], aArr[3];
#pragma unroll
    for (int j = 0; j < 3; ++j) {
      int idx = w + 4 * j;
      sArr[j] = (const char*)Kp; dArr[j] = 0; aArr[j] = 0;
      if (idx < 6) {
        int p = idx * 1024 + l * 16;
        int row = p / 192;
        int slot = (p % 192) >> 4;
        int sw = slot ^ ((row >> 1) & 3);
        sArr[j] = (const char*)Kp + ((size_t)h * SEQ + seg * SEGL + row) * 192 + sw * 16;
        aArr[j] = 32 * 192;
        dArr[j] = idx * 1024;
      } else if (idx < 11) {
        int j3 = idx - 6;
        int row = j3 * 16 + (l >> 2);
        int slot = l & 3;
        int sw = slot ^ ((row >> 1) & 3);
        sArr[j] = (const char*)Vt + ((size_t)h * HD + row) * (SEQ * 2) +
                  (size_t)seg * SEGL * 2 + sw * 16;
        aArr[j] = 64;
        dArr[j] = KTILE_B + j3 * 1024;
      }
    }
    src0 = sArr[0]; src1 = sArr[1]; src2 = sArr[2];
    dst0 = dArr[0]; dst1 = dArr[1]; dst2 = dArr[2];
    adv0 = aArr[0]; adv1 = aArr[1]; adv2 = aArr[2];
  }

#define STAGE(pb, tt)                                                          \
  do {                                                                         \
    __builtin_amdgcn_global_load_lds(                                          \
        (const __attribute__((address_space(1))) void*)(src0 + (size_t)(tt) * adv0), \
        (__attribute__((address_space(3))) void*)(smem + (pb) * BUF_B + dst0), \
        16, 0, 0);                                                             \
    __builtin_amdgcn_global_load_lds(                                          \
        (const __attribute__((address_space(1))) void*)(src1 + (size_t)(tt) * adv1), \
        (__attribute__((address_space(3))) void*)(smem + (pb) * BUF_B + dst1), \
        16, 0, 0);                                                             \
    if (nld == 3)                                                              \
      __builtin_amdgcn_global_load_lds(                                        \
          (const __attribute__((address_space(1))) void*)(src2 + (size_t)(tt) * adv2), \
          (__attribute__((address_space(3))) void*)(smem + (pb) * BUF_B + dst2), \
          16, 0, 0);                                                           \
  } while (0)

  f32x4 accO[5] = {};
  float lpart = 0.f;

  STAGE(0, 0);
  __syncthreads();

  const int NSTEP = SEGL / 32;
  for (int step = 0; step < NSTEP; ++step) {
    const int pb = step & 1;
    if (step + 1 < NSTEP) STAGE(pb ^ 1, step + 1);

    const char* Ks = smem + pb * BUF_B;
    const char* Vs = smem + pb * BUF_B + KTILE_B;

    f32x4 st[2] = {};
#pragma unroll
    for (int sub = 0; sub < 2; ++sub)
#pragma unroll
      for (int dt = 0; dt < 3; ++dt) {
        short8 kf = *(const short8*)(Ks + (sub * 16 + q) * 192 + dt * 64 + gm * 16);
        st[sub] = mfma16(kf, qf[dt], st[sub]);
      }

    short4v pk[2];
#pragma unroll
    for (int sub = 0; sub < 2; ++sub)
#pragma unroll
      for (int r = 0; r < 4; ++r) {
        float p = __builtin_exp2f(st[sub][r] * L2E);
        lpart += p;
        pk[sub][r] = f2bf(p);
      }

    *(short4v*)(&Pbuf[pb][w][q][g * 4]) = pk[0];
    *(short4v*)(&Pbuf[pb][w][q][16 + g * 4]) = pk[1];
    asm volatile("s_waitcnt lgkmcnt(0)" ::: "memory");

    short8 pa = *(const short8*)(&Pbuf[pb][w][q][g * 8]);
#pragma unroll
    for (int dt = 0; dt < 5; ++dt) {
      short8 vf = *(const short8*)(Vs + (dt * 16 + q) * 64 + gm * 16);
      accO[dt] = mfma16(pa, vf, accO[dt]);
    }
    __syncthreads();
  }
#undef STAGE

  lpart += __shfl_xor(lpart, 16);
  lpart += __shfl_xor(lpart, 32);
  float linv = 1.0f / lpart;
  float lq[4];
#pragma unroll
  for (int r = 0; r < 4; ++r) lq[r] = __shfl(linv, g * 4 + r);
#pragma unroll
  for (int dt = 0; dt < 5; ++dt)
#pragma unroll
    for (int r = 0; r < 4; ++r) {
      int row = qrow + g * 4 + r;
      att[(size_t)row * DIM + h * HD + dt * 16 + q] = f2bf(accO[dt][r] * lq[r]);
    }
}

// ---------------- launch -----------------------------------------------------
extern "C" void kernel_launch(void* const* d_in, const int* in_sizes, int n_in,
                              void* d_out, int out_size, void* d_ws, size_t ws_size,
                              hipStream_t stream) {
  const float* hidden = (const float*)d_in[0];
  const float* cosp   = (const float*)d_in[1];
  const float* sinp   = (const float*)d_in[2];
  const float* w_qkv  = (const float*)d_in[3];
  const float* b_qkv  = (const float*)d_in[4];
  const float* w_proj = (const float*)d_in[5];
  const float* b_proj = (const float*)d_in[6];
  float* out = (float*)d_out;

  char* ws = (char*)d_ws;
  short* hidden_b = (short*)(ws);
  short* wqkv_b   = (short*)(ws + 7864320);
  short* wproj_b  = (short*)(ws + 17694720);
  short* qkv_b    = (short*)(ws + 20971520);
  short* Qp       = (short*)(ws + 44564480);
  short* Kp       = (short*)(ws + 54001664);
  short* Vt       = (short*)(ws + 63438848);
  short* att      = (short*)(ws + 71303168);

  const int na = SEQ * DIM / 4, nb = QKVN * DIM / 4;
  cvt2<<<dim3((na + nb + 255) / 256), 256, 0, stream>>>(
      hidden, hidden_b, na, w_qkv, wqkv_b, nb);

  gemm_qkv_8ph<<<dim3(240), 512, 0, stream>>>(
      hidden_b, wqkv_b, b_qkv, qkv_b, QKVN, DIM, 12, 30);

  prep_fused<<<dim3(NB_ROPE + NB_VT + NB_CVT), 256, 0, stream>>>(
      qkv_b, cosp, sinp, Qp, Kp, Vt, w_proj, wproj_b);

  attn_kernel<<<dim3(768), 256, 0, stream>>>(Qp, Kp, Vt, att);

  gemm_bt<0><<<dim3(240), 256, 0, stream>>>(
      att, wproj_b, b_proj, out, SEQ, DIM, DIM, 10, 30);
}

// Round 15
// 112.610 us; speedup vs baseline: 1.0483x; 1.0483x over previous
//
#include <hip/hip_runtime.h>
#include <cstdint>
#include <cstddef>

#define SEQ   3072
#define DIM   1280
#define NH    16
#define HD    80
#define HDP   96
#define NSEG  4
#define SEGL  768
#define QKVN  3840

typedef __attribute__((ext_vector_type(8))) short short8;
typedef __attribute__((ext_vector_type(4))) short short4v;
typedef __attribute__((ext_vector_type(4))) float f32x4;
typedef __bf16 bf16x8 __attribute__((ext_vector_type(8)));

__device__ __forceinline__ f32x4 mfma16(short8 a, short8 b, f32x4 c) {
  return __builtin_amdgcn_mfma_f32_16x16x32_bf16(
      __builtin_bit_cast(bf16x8, a), __builtin_bit_cast(bf16x8, b), c, 0, 0, 0);
}

__device__ __forceinline__ float bf2f(short u) {
  union { unsigned int i; float f; } v;
  v.i = ((unsigned int)(unsigned short)u) << 16;
  return v.f;
}
__device__ __forceinline__ short f2bf(float f) {
  union { float f; unsigned int i; } v; v.f = f;
  unsigned int x = v.i;
  unsigned int r = (x + 0x7fffu + ((x >> 16) & 1u)) >> 16;
  return (short)r;
}

// ---------------- fp32 -> bf16 convert (hidden + w_qkv) ---------------------
__global__ void cvt2(const float* __restrict__ a, short* __restrict__ oa, int na,
                     const float* __restrict__ b, short* __restrict__ ob, int nb) {
  int i = blockIdx.x * 256 + threadIdx.x;
  const float* src; short* dst; int off;
  if (i < na) { src = a; dst = oa; off = i; }
  else if (i < na + nb) { src = b; dst = ob; off = i - na; }
  else return;
  float4 v = ((const float4*)src)[off];
  short4v o;
  o[0] = f2bf(v.x); o[1] = f2bf(v.y); o[2] = f2bf(v.z); o[3] = f2bf(v.w);
  ((short4v*)dst)[off] = o;
}

// ============ QKV GEMM: 256x192 tile, BK=64, 2-phase / 2-barrier K-tiles ====
#define NKT 20   // K=1280/64

__global__ __launch_bounds__(512, 2)
void gemm_qkv_8ph(const short* __restrict__ A, const short* __restrict__ B,
                  const float* __restrict__ bias, short* __restrict__ C,
                  int N, int K, int nbm, int cpx) {
  __shared__ short As[2][256 * 64];
  __shared__ short Bs[2][192 * 64];
  const int T = threadIdx.x;
  const int w = T >> 6, l = T & 63, g = l >> 4, q = l & 15;
  const int wr = w >> 2, wc = w & 3;
  const int bid = blockIdx.x;
  const int swz = (bid & 7) * cpx + (bid >> 3);
  const int bm = (swz % nbm) * 256;
  const int bn = (swz / nbm) * 192;

  const int sr = T >> 3, ps = T & 7;
  const int gsrc = ps ^ (sr & 7);
  const short* srcA = A + (size_t)(bm + sr) * K + gsrc * 8;
  const short* srcB = B + (size_t)(bn + sr) * K + gsrc * 8;

#define STAGE_B(tt, pb)                                                        \
  do {                                                                         \
    _Pragma("unroll") for (int j = 0; j < 3; ++j)                              \
      __builtin_amdgcn_global_load_lds(                                        \
        (const __attribute__((address_space(1))) void*)(srcB + (size_t)j * 64 * K + (size_t)(tt) * 64), \
        (__attribute__((address_space(3))) void*)(&Bs[pb][j * 4096 + T * 8]),  \
        16, 0, 0);                                                             \
  } while (0)
#define STAGE_AE(tt, pb)                                                       \
  do {                                                                         \
    __builtin_amdgcn_global_load_lds(                                          \
        (const __attribute__((address_space(1))) void*)(srcA + (size_t)(tt) * 64), \
        (__attribute__((address_space(3))) void*)(&As[pb][T * 8]), 16, 0, 0);  \
    __builtin_amdgcn_global_load_lds(                                          \
        (const __attribute__((address_space(1))) void*)(srcA + (size_t)2 * 64 * K + (size_t)(tt) * 64), \
        (__attribute__((address_space(3))) void*)(&As[pb][2 * 4096 + T * 8]),  \
        16, 0, 0);                                                             \
  } while (0)
#define STAGE_AL(tt, pb)                                                       \
  do {                                                                         \
    __builtin_amdgcn_global_load_lds(                                          \
        (const __attribute__((address_space(1))) void*)(srcA + (size_t)1 * 64 * K + (size_t)(tt) * 64), \
        (__attribute__((address_space(3))) void*)(&As[pb][1 * 4096 + T * 8]),  \
        16, 0, 0);                                                             \
    __builtin_amdgcn_global_load_lds(                                          \
        (const __attribute__((address_space(1))) void*)(srcA + (size_t)3 * 64 * K + (size_t)(tt) * 64), \
        (__attribute__((address_space(3))) void*)(&As[pb][3 * 4096 + T * 8]),  \
        16, 0, 0);                                                             \
  } while (0)

  const int s0e = (g ^ (q & 7)) * 8;
  const int rowAe = (wr * 128 + q) * 64;
  const int rowBe = (wc * 48 + q) * 64;

  f32x4 acc[8][3] = {};

  STAGE_B(0, 0); STAGE_AE(0, 0); STAGE_AL(0, 0);
  asm volatile("s_waitcnt vmcnt(0)" ::: "memory");
  __builtin_amdgcn_s_barrier();

  for (int t = 0; t < NKT; ++t) {
    const int p = t & 1;
    const bool more = (t + 1 < NKT);

    short8 bfr[3][2], af[4][2];

    // ---- phase 0 ----
#pragma unroll
    for (int n = 0; n < 3; ++n)
#pragma unroll
      for (int kk = 0; kk < 2; ++kk)
        bfr[n][kk] = *(const short8*)(&Bs[p][rowBe + n * 1024 + (s0e ^ (kk * 32))]);
#pragma unroll
    for (int m = 0; m < 4; ++m)
#pragma unroll
      for (int kk = 0; kk < 2; ++kk)
        af[m][kk] = *(const short8*)(&As[p][rowAe + m * 1024 + (s0e ^ (kk * 32))]);
    if (more) { STAGE_B(t + 1, p ^ 1); STAGE_AE(t + 1, p ^ 1); }
    if (more) asm volatile("s_waitcnt vmcnt(5)" ::: "memory");
    else      asm volatile("s_waitcnt vmcnt(0)" ::: "memory");
    __builtin_amdgcn_s_barrier();
    __builtin_amdgcn_s_setprio(1);
#pragma unroll
    for (int m = 0; m < 4; ++m)
#pragma unroll
      for (int n = 0; n < 3; ++n)
#pragma unroll
        for (int kk = 0; kk < 2; ++kk)
          acc[m][n] = mfma16(af[m][kk], bfr[n][kk], acc[m][n]);
    __builtin_amdgcn_s_setprio(0);

    // ---- phase 1 ----
#pragma unroll
    for (int m = 0; m < 4; ++m)
#pragma unroll
      for (int kk = 0; kk < 2; ++kk)
        af[m][kk] = *(const short8*)(&As[p][rowAe + (m + 4) * 1024 + (s0e ^ (kk * 32))]);
    if (more) {
      STAGE_AL(t + 1, p ^ 1);
      asm volatile("s_waitcnt vmcnt(2)" ::: "memory");
    }
    __builtin_amdgcn_s_barrier();
    __builtin_amdgcn_s_setprio(1);
#pragma unroll
    for (int m = 0; m < 4; ++m)
#pragma unroll
      for (int n = 0; n < 3; ++n)
#pragma unroll
        for (int kk = 0; kk < 2; ++kk)
          acc[m + 4][n] = mfma16(af[m][kk], bfr[n][kk], acc[m + 4][n]);
    __builtin_amdgcn_s_setprio(0);
  }

  float bv[3];
#pragma unroll
  for (int n = 0; n < 3; ++n) bv[n] = bias[bn + wc * 48 + n * 16 + q];
#pragma unroll
  for (int m = 0; m < 8; ++m)
#pragma unroll
    for (int n = 0; n < 3; ++n)
#pragma unroll
      for (int r = 0; r < 4; ++r) {
        int row = bm + wr * 128 + m * 16 + g * 4 + r;
        int col = bn + wc * 48 + n * 16 + q;
        C[(size_t)row * N + col] = f2bf(acc[m][n][r] + bv[n]);
      }
#undef STAGE_B
#undef STAGE_AE
#undef STAGE_AL
}

// ---------------- 128^2 double-buffered 2-phase GEMM (proj) -----------------
template<int OUT_BF16>
__global__ __launch_bounds__(256, 2)
void gemm_bt(const short* __restrict__ A, const short* __restrict__ B,
             const float* __restrict__ bias, void* __restrict__ Cout,
             int M, int N, int K, int nbx, int cpx) {
  __shared__ short As[2][128 * 32];
  __shared__ short Bs[2][128 * 32];
  const int t = threadIdx.x;
  const int w = t >> 6, l = t & 63;
  const int g = l >> 4, q = l & 15;
  const int wr = w >> 1, wc = w & 1;

  const int bid = blockIdx.x;
  const int swz = (bid & 7) * cpx + (bid >> 3);
  const int bm = (swz / nbx) * 128, bn = (swz % nbx) * 128;

  const int srow = l >> 2;
  const int sg = (l & 3) ^ ((l >> 3) & 3);
  const int gsw = g ^ ((q >> 1) & 3);

  const int c0 = w * 2, c1 = w * 2 + 1;
  const short* gA0 = A + (size_t)(bm + c0 * 16 + srow) * K + sg * 8;
  const short* gA1 = A + (size_t)(bm + c1 * 16 + srow) * K + sg * 8;
  const short* gB0 = B + (size_t)(bn + c0 * 16 + srow) * K + sg * 8;
  const short* gB1 = B + (size_t)(bn + c1 * 16 + srow) * K + sg * 8;

#define PSTAGE(kt, pb)                                                         \
  do {                                                                         \
    __builtin_amdgcn_global_load_lds(                                          \
        (const __attribute__((address_space(1))) void*)(gA0 + (size_t)(kt) * 32), \
        (__attribute__((address_space(3))) void*)(&As[pb][c0 * 512 + (l & 3) * 8 + srow * 32]), 16, 0, 0); \
    __builtin_amdgcn_global_load_lds(                                          \
        (const __attribute__((address_space(1))) void*)(gA1 + (size_t)(kt) * 32), \
        (__attribute__((address_space(3))) void*)(&As[pb][c1 * 512 + (l & 3) * 8 + srow * 32]), 16, 0, 0); \
    __builtin_amdgcn_global_load_lds(                                          \
        (const __attribute__((address_space(1))) void*)(gB0 + (size_t)(kt) * 32), \
        (__attribute__((address_space(3))) void*)(&Bs[pb][c0 * 512 + (l & 3) * 8 + srow * 32]), 16, 0, 0); \
    __builtin_amdgcn_global_load_lds(                                          \
        (const __attribute__((address_space(1))) void*)(gB1 + (size_t)(kt) * 32), \
        (__attribute__((address_space(3))) void*)(&Bs[pb][c1 * 512 + (l & 3) * 8 + srow * 32]), 16, 0, 0); \
  } while (0)

  f32x4 acc[4][4] = {};
  const int nkt = K / 32;

  PSTAGE(0, 0);
  __syncthreads();

  for (int kt = 0; kt < nkt; ++kt) {
    const int p = kt & 1;
    if (kt + 1 < nkt) PSTAGE(kt + 1, p ^ 1);

    short8 af[4], bfr[4];
#pragma unroll
    for (int m = 0; m < 4; ++m)
      af[m] = *(const short8*)(&As[p][(wr * 64 + m * 16 + q) * 32 + gsw * 8]);
#pragma unroll
    for (int n = 0; n < 4; ++n)
      bfr[n] = *(const short8*)(&Bs[p][(wc * 64 + n * 16 + q) * 32 + gsw * 8]);
#pragma unroll
    for (int m = 0; m < 4; ++m)
#pragma unroll
      for (int n = 0; n < 4; ++n)
        acc[m][n] = mfma16(af[m], bfr[n], acc[m][n]);
    __syncthreads();
  }
#undef PSTAGE

  float bv[4];
#pragma unroll
  for (int n = 0; n < 4; ++n) bv[n] = bias[bn + wc * 64 + n * 16 + q];

#pragma unroll
  for (int m = 0; m < 4; ++m)
#pragma unroll
    for (int n = 0; n < 4; ++n)
#pragma unroll
      for (int r = 0; r < 4; ++r) {
        int row = bm + wr * 64 + m * 16 + g * 4 + r;
        int col = bn + wc * 64 + n * 16 + q;
        float v = acc[m][n][r] + bv[n];
        if (OUT_BF16)
          ((short*)Cout)[(size_t)row * N + col] = f2bf(v);
        else
          ((float*)Cout)[(size_t)row * N + col] = v;
      }
}

// ---------- fused prep: RoPE(Q,K) + V-transpose + cvt(w_proj) ---------------
#define NB_ROPE 2304
#define NB_VT   768
#define NB_CVT  1600

__global__ __launch_bounds__(256)
void prep_fused(const short* __restrict__ qkv,
                const float* __restrict__ cosp, const float* __restrict__ sinp,
                short* __restrict__ Qp, short* __restrict__ Kp,
                short* __restrict__ Vt,
                const float* __restrict__ wproj, short* __restrict__ wproj_b) {
  __shared__ short T[80][68];
  const int b = blockIdx.x, t = threadIdx.x;

  if (b < NB_ROPE) {
    int tid = b * 256 + t;
    if (tid >= SEQ * NH * 12) return;
    int j = tid % 12;
    int sh = tid / 12;
    int h = sh % NH, s = sh / NH;
    size_t qbase = ((size_t)h * SEQ + s) * HDP;
    if (j >= 10) {
      short8 z = {};
      *(short8*)(Qp + qbase + 80 + (j - 10) * 8) = z;
      *(short8*)(Kp + qbase + 80 + (j - 10) * 8) = z;
      return;
    }
    const int d0 = j * 4;
    const int gb = s * QKVN + h * HD;
    short4v qlo = *(const short4v*)(qkv + gb + d0);
    short4v qhi = *(const short4v*)(qkv + gb + d0 + 40);
    short4v klo = *(const short4v*)(qkv + gb + DIM + d0);
    short4v khi = *(const short4v*)(qkv + gb + DIM + d0 + 40);
    float4 cl = *(const float4*)(cosp + s * HD + d0);
    float4 ch = *(const float4*)(cosp + s * HD + d0 + 40);
    float4 sl = *(const float4*)(sinp + s * HD + d0);
    float4 sh4 = *(const float4*)(sinp + s * HD + d0 + 40);
    const float scale = 0.11180339887498948f;  // 80^-0.5 folded into Q
    short4v qolo, qohi, kolo, kohi;
#pragma unroll
    for (int e = 0; e < 4; ++e) {
      float cle = ((const float*)&cl)[e], che = ((const float*)&ch)[e];
      float sle = ((const float*)&sl)[e], she = ((const float*)&sh4)[e];
      float ql = bf2f(qlo[e]), qh = bf2f(qhi[e]);
      float kl = bf2f(klo[e]), kh = bf2f(khi[e]);
      qolo[e] = f2bf((ql * cle - qh * sle) * scale);
      qohi[e] = f2bf((qh * che + ql * she) * scale);
      kolo[e] = f2bf(kl * cle - kh * sle);
      kohi[e] = f2bf(kh * che + kl * she);
    }
    *(short4v*)(Qp + qbase + d0) = qolo;
    *(short4v*)(Qp + qbase + d0 + 40) = qohi;
    *(short4v*)(Kp + qbase + d0) = kolo;
    *(short4v*)(Kp + qbase + d0 + 40) = kohi;
  } else if (b < NB_ROPE + NB_VT) {
    int vb = b - NB_ROPE;
    const int sblk = vb % 48, h = vb / 48;
    const int s0 = sblk * 64;
#pragma unroll
    for (int j = 0; j < 5; ++j) {
      int i = j * 256 + t;
      int row = i / 20, c4 = i % 20;
      short4v v = *(const short4v*)(qkv + (size_t)(s0 + row) * QKVN + 2 * DIM + h * HD + c4 * 4);
#pragma unroll
      for (int e = 0; e < 4; ++e) T[c4 * 4 + e][row] = v[e];
    }
    __syncthreads();
#pragma unroll
    for (int j = 0; j < 5; ++j) {
      int i = j * 256 + t;
      int d = i / 16, c4 = i % 16;
      short4v v = *(const short4v*)(&T[d][c4 * 4]);
      *(short4v*)(Vt + ((size_t)h * HD + d) * SEQ + s0 + c4 * 4) = v;
    }
  } else {
    int i = (b - NB_ROPE - NB_VT) * 256 + t;
    if (i >= DIM * DIM / 4) return;
    float4 v = ((const float4*)wproj)[i];
    short4v o;
    o[0] = f2bf(v.x); o[1] = f2bf(v.y); o[2] = f2bf(v.z); o[3] = f2bf(v.w);
    ((short4v*)wproj_b)[i] = o;
  }
}

// ---------------- flash attention (16x16, QBLK=64, double-buffered) ---------
#define KTILE_B  6144
#define VTILE_B  5120
#define BUF_B    11264

__global__ __launch_bounds__(256, 4)
void attn_kernel(const short* __restrict__ Qp, const short* __restrict__ Kp,
                 const short* __restrict__ Vt, short* __restrict__ att) {
  __shared__ __align__(16) char smem[2 * BUF_B];
  __shared__ short Pbuf[2][4][16][36];

  const int orig = blockIdx.x;
  const int lg = (orig & 7) * 96 + (orig >> 3);
  const int qt = lg % 12;
  const int hs = lg / 12;
  const int seg = hs & 3, h = hs >> 2;

  const int t = threadIdx.x, w = t >> 6, l = t & 63;
  const int g = l >> 4, q = l & 15;
  const int m4 = (q >> 1) & 3;
  const int gm = g ^ m4;
  const int qrow = seg * SEGL + qt * 64 + w * 16;
  const float L2E = 1.4426950408889634f;

  short8 qf[3];
#pragma unroll
  for (int dt = 0; dt < 3; ++dt)
    qf[dt] = *(const short8*)(Qp + ((size_t)h * SEQ + qrow + q) * HDP + dt * 32 + g * 8);

  const char* src0; const char* src1; const char* src2;
  int dst0, dst1, dst2, adv0, adv1, adv2;
  const int nld = (w < 3) ? 3 : 2;
  {
    const char* sArr[3]; int dArr[3], aArr[3];
#pragma unroll
    for (int j = 0; j < 3; ++j) {
      int idx = w + 4 * j;
      sArr[j] = (const char*)Kp; dArr[j] = 0; aArr[j] = 0;
      if (idx < 6) {
        int p = idx * 1024 + l * 16;
        int row = p / 192;
        int slot = (p % 192) >> 4;
        int sw = slot ^ ((row >> 1) & 3);
        sArr[j] = (const char*)Kp + ((size_t)h * SEQ + seg * SEGL + row) * 192 + sw * 16;
        aArr[j] = 32 * 192;
        dArr[j] = idx * 1024;
      } else if (idx < 11) {
        int j3 = idx - 6;
        int row = j3 * 16 + (l >> 2);
        int slot = l & 3;
        int sw = slot ^ ((row >> 1) & 3);
        sArr[j] = (const char*)Vt + ((size_t)h * HD + row) * (SEQ * 2) +
                  (size_t)seg * SEGL * 2 + sw * 16;
        aArr[j] = 64;
        dArr[j] = KTILE_B + j3 * 1024;
      }
    }
    src0 = sArr[0]; src1 = sArr[1]; src2 = sArr[2];
    dst0 = dArr[0]; dst1 = dArr[1]; dst2 = dArr[2];
    adv0 = aArr[0]; adv1 = aArr[1]; adv2 = aArr[2];
  }

#define STAGE(pb, tt)                                                          \
  do {                                                                         \
    __builtin_amdgcn_global_load_lds(                                          \
        (const __attribute__((address_space(1))) void*)(src0 + (size_t)(tt) * adv0), \
        (__attribute__((address_space(3))) void*)(smem + (pb) * BUF_B + dst0), \
        16, 0, 0);                                                             \
    __builtin_amdgcn_global_load_lds(                                          \
        (const __attribute__((address_space(1))) void*)(src1 + (size_t)(tt) * adv1), \
        (__attribute__((address_space(3))) void*)(smem + (pb) * BUF_B + dst1), \
        16, 0, 0);                                                             \
    if (nld == 3)                                                              \
      __builtin_amdgcn_global_load_lds(                                        \
          (const __attribute__((address_space(1))) void*)(src2 + (size_t)(tt) * adv2), \
          (__attribute__((address_space(3))) void*)(smem + (pb) * BUF_B + dst2), \
          16, 0, 0);                                                           \
  } while (0)

  f32x4 accO[5] = {};
  float lpart = 0.f;

  STAGE(0, 0);
  __syncthreads();

  const int NSTEP = SEGL / 32;
  for (int step = 0; step < NSTEP; ++step) {
    const int pb = step & 1;
    if (step + 1 < NSTEP) STAGE(pb ^ 1, step + 1);

    const char* Ks = smem + pb * BUF_B;
    const char* Vs = smem + pb * BUF_B + KTILE_B;

    f32x4 st[2] = {};
#pragma unroll
    for (int sub = 0; sub < 2; ++sub)
#pragma unroll
      for (int dt = 0; dt < 3; ++dt) {
        short8 kf = *(const short8*)(Ks + (sub * 16 + q) * 192 + dt * 64 + gm * 16);
        st[sub] = mfma16(kf, qf[dt], st[sub]);
      }

    short4v pk[2];
#pragma unroll
    for (int sub = 0; sub < 2; ++sub)
#pragma unroll
      for (int r = 0; r < 4; ++r) {
        float p = __builtin_exp2f(st[sub][r] * L2E);
        lpart += p;
        pk[sub][r] = f2bf(p);
      }

    *(short4v*)(&Pbuf[pb][w][q][g * 4]) = pk[0];
    *(short4v*)(&Pbuf[pb][w][q][16 + g * 4]) = pk[1];
    asm volatile("s_waitcnt lgkmcnt(0)" ::: "memory");

    short8 pa = *(const short8*)(&Pbuf[pb][w][q][g * 8]);
#pragma unroll
    for (int dt = 0; dt < 5; ++dt) {
      short8 vf = *(const short8*)(Vs + (dt * 16 + q) * 64 + gm * 16);
      accO[dt] = mfma16(pa, vf, accO[dt]);
    }
    __syncthreads();
  }
#undef STAGE

  lpart += __shfl_xor(lpart, 16);
  lpart += __shfl_xor(lpart, 32);
  float linv = 1.0f / lpart;
  float lq[4];
#pragma unroll
  for (int r = 0; r < 4; ++r) lq[r] = __shfl(linv, g * 4 + r);
#pragma unroll
  for (int dt = 0; dt < 5; ++dt)
#pragma unroll
    for (int r = 0; r < 4; ++r) {
      int row = qrow + g * 4 + r;
      att[(size_t)row * DIM + h * HD + dt * 16 + q] = f2bf(accO[dt][r] * lq[r]);
    }
}

// ---------------- launch -----------------------------------------------------
extern "C" void kernel_launch(void* const* d_in, const int* in_sizes, int n_in,
                              void* d_out, int out_size, void* d_ws, size_t ws_size,
                              hipStream_t stream) {
  const float* hidden = (const float*)d_in[0];
  const float* cosp   = (const float*)d_in[1];
  const float* sinp   = (const float*)d_in[2];
  const float* w_qkv  = (const float*)d_in[3];
  const float* b_qkv  = (const float*)d_in[4];
  const float* w_proj = (const float*)d_in[5];
  const float* b_proj = (const float*)d_in[6];
  float* out = (float*)d_out;

  char* ws = (char*)d_ws;
  short* hidden_b = (short*)(ws);
  short* wqkv_b   = (short*)(ws + 7864320);
  short* wproj_b  = (short*)(ws + 17694720);
  short* qkv_b    = (short*)(ws + 20971520);
  short* Qp       = (short*)(ws + 44564480);
  short* Kp       = (short*)(ws + 54001664);
  short* Vt       = (short*)(ws + 63438848);
  short* att      = (short*)(ws + 71303168);

  const int na = SEQ * DIM / 4, nb = QKVN * DIM / 4;
  cvt2<<<dim3((na + nb + 255) / 256), 256, 0, stream>>>(
      hidden, hidden_b, na, w_qkv, wqkv_b, nb);

  gemm_qkv_8ph<<<dim3(240), 512, 0, stream>>>(
      hidden_b, wqkv_b, b_qkv, qkv_b, QKVN, DIM, 12, 30);

  prep_fused<<<dim3(NB_ROPE + NB_VT + NB_CVT), 256, 0, stream>>>(
      qkv_b, cosp, sinp, Qp, Kp, Vt, w_proj, wproj_b);

  attn_kernel<<<dim3(768), 256, 0, stream>>>(Qp, Kp, Vt, att);

  gemm_bt<0><<<dim3(240), 256, 0, stream>>>(
      att, wproj_b, b_proj, out, SEQ, DIM, DIM, 10, 30);
}